// Round 1
// baseline (265.405 us; speedup 1.0000x reference)
//
#include <hip/hip_runtime.h>

#define K_FEATS 256
#define C_FEATS 64
#define ROWS_PER_BLOCK 16

// ---------------------------------------------------------------------------
// Kernel 0: zero the aggregation buffer (d_ws). float4 grid-stride.
// ---------------------------------------------------------------------------
__global__ __launch_bounds__(256) void zero_kernel(float4* __restrict__ p, int n4) {
    for (int i = blockIdx.x * blockDim.x + threadIdx.x; i < n4;
         i += gridDim.x * blockDim.x) {
        p[i] = make_float4(0.f, 0.f, 0.f, 0.f);
    }
}

// ---------------------------------------------------------------------------
// Kernel 1: hwn[n][c] = norm[n] * sum_k h[n][k] * w[k][c]
// One block of 256 threads handles 16 rows. W (64 KB) staged in LDS once per
// block; the 16x256 h tile (16 KB, contiguous) staged in LDS. Each thread
// owns 4 rows x 1 col. LDS access: w read is 2-way bank aliased (free on
// CDNA4), h read is wave-uniform broadcast (free).
// ---------------------------------------------------------------------------
__global__ __launch_bounds__(256) void gemm_norm_kernel(
    const float* __restrict__ h, const float* __restrict__ w,
    const float* __restrict__ norm, float* __restrict__ hwn, int n_nodes)
{
    __shared__ float w_lds[K_FEATS * C_FEATS];          // 64 KB
    __shared__ float h_lds[ROWS_PER_BLOCK * K_FEATS];   // 16 KB

    const int tid = threadIdx.x;
    // stage W: 16384 floats = 4096 float4
    for (int i = tid; i < K_FEATS * C_FEATS / 4; i += 256) {
        reinterpret_cast<float4*>(w_lds)[i] = reinterpret_cast<const float4*>(w)[i];
    }
    const int row0 = blockIdx.x * ROWS_PER_BLOCK;
    // stage h tile: rows are contiguous, 1024 float4
    const float4* hsrc = reinterpret_cast<const float4*>(h + (size_t)row0 * K_FEATS);
    const int rows_here = min(ROWS_PER_BLOCK, n_nodes - row0);
    for (int i = tid; i < rows_here * K_FEATS / 4; i += 256) {
        reinterpret_cast<float4*>(h_lds)[i] = hsrc[i];
    }
    __syncthreads();

    const int c  = tid & 63;
    const int rg = tid >> 6;           // wave id: 4 rows per wave
    float acc0 = 0.f, acc1 = 0.f, acc2 = 0.f, acc3 = 0.f;
    const float* h0 = &h_lds[(rg * 4 + 0) * K_FEATS];
    const float* h1 = &h_lds[(rg * 4 + 1) * K_FEATS];
    const float* h2 = &h_lds[(rg * 4 + 2) * K_FEATS];
    const float* h3 = &h_lds[(rg * 4 + 3) * K_FEATS];
    #pragma unroll 8
    for (int k = 0; k < K_FEATS; ++k) {
        const float wv = w_lds[k * C_FEATS + c];
        acc0 = fmaf(h0[k], wv, acc0);
        acc1 = fmaf(h1[k], wv, acc1);
        acc2 = fmaf(h2[k], wv, acc2);
        acc3 = fmaf(h3[k], wv, acc3);
    }
    const int r = row0 + rg * 4;
    if (r + 0 < n_nodes) hwn[(size_t)(r + 0) * C_FEATS + c] = acc0 * norm[r + 0];
    if (r + 1 < n_nodes) hwn[(size_t)(r + 1) * C_FEATS + c] = acc1 * norm[r + 1];
    if (r + 2 < n_nodes) hwn[(size_t)(r + 2) * C_FEATS + c] = acc2 * norm[r + 2];
    if (r + 3 < n_nodes) hwn[(size_t)(r + 3) * C_FEATS + c] = acc3 * norm[r + 3];
}

// ---------------------------------------------------------------------------
// Kernel 2: for each edge e: agg[dst[e]][:] += hwn[src[e]][:]
// One 64-lane wave per edge, lane = feature. 4 edges per 256-thread block.
// ---------------------------------------------------------------------------
__global__ __launch_bounds__(256) void edge_scatter_kernel(
    const float* __restrict__ hwn, const int* __restrict__ src,
    const int* __restrict__ dst, float* __restrict__ agg, int n_edges)
{
    const int e = blockIdx.x * 4 + (threadIdx.x >> 6);
    if (e >= n_edges) return;
    const int lane = threadIdx.x & 63;
    const int s = src[e];
    const int d = dst[e];
    const float v = hwn[(size_t)s * C_FEATS + lane];
    atomicAdd(&agg[(size_t)d * C_FEATS + lane], v);
}

// ---------------------------------------------------------------------------
// Kernel 3: out[n][c] = relu(agg[n][c] * norm[n] + bias[c]); float4 per thread
// ---------------------------------------------------------------------------
__global__ __launch_bounds__(256) void finalize_kernel(
    const float* __restrict__ agg, const float* __restrict__ norm,
    const float* __restrict__ bias, float* __restrict__ out, int n_nodes)
{
    const int i = blockIdx.x * blockDim.x + threadIdx.x;   // one float4
    const int total4 = n_nodes * (C_FEATS / 4);
    if (i >= total4) return;
    const int n  = i >> 4;          // 16 float4 per row
    const int c4 = (i & 15) * 4;
    const float4 a = reinterpret_cast<const float4*>(agg)[i];
    const float nv = norm[n];
    const float4 b = *reinterpret_cast<const float4*>(bias + c4);
    float4 o;
    o.x = fmaxf(fmaf(a.x, nv, b.x), 0.f);
    o.y = fmaxf(fmaf(a.y, nv, b.y), 0.f);
    o.z = fmaxf(fmaf(a.z, nv, b.z), 0.f);
    o.w = fmaxf(fmaf(a.w, nv, b.w), 0.f);
    reinterpret_cast<float4*>(out)[i] = o;
}

extern "C" void kernel_launch(void* const* d_in, const int* in_sizes, int n_in,
                              void* d_out, int out_size, void* d_ws, size_t ws_size,
                              hipStream_t stream) {
    const float* h      = (const float*)d_in[0];
    const float* norm   = (const float*)d_in[1];
    const int*   src    = (const int*)d_in[2];
    const int*   dst    = (const int*)d_in[3];
    const float* weight = (const float*)d_in[4];
    const float* bias   = (const float*)d_in[5];

    const int n_nodes = in_sizes[1];
    const int n_edges = in_sizes[2];

    float* hwn = (float*)d_out;   // reuse output buffer as projection scratch
    float* agg = (float*)d_ws;    // n_nodes * 64 floats of workspace

    // 0) zero agg
    {
        const int n4 = n_nodes * (C_FEATS / 4);
        const int blocks = min((n4 + 255) / 256, 2048);
        zero_kernel<<<blocks, 256, 0, stream>>>((float4*)agg, n4);
    }
    // 1) projection (+ fold in norm[src])
    {
        const int blocks = (n_nodes + ROWS_PER_BLOCK - 1) / ROWS_PER_BLOCK;
        gemm_norm_kernel<<<blocks, 256, 0, stream>>>(h, weight, norm, hwn, n_nodes);
    }
    // 2) edge scatter (atomic)
    {
        const int blocks = (n_edges + 3) / 4;
        edge_scatter_kernel<<<blocks, 256, 0, stream>>>(hwn, src, dst, agg, n_edges);
    }
    // 3) finalize
    {
        const int total4 = n_nodes * (C_FEATS / 4);
        const int blocks = (total4 + 255) / 256;
        finalize_kernel<<<blocks, 256, 0, stream>>>(agg, norm, bias, (float*)d_out, n_nodes);
    }
}

// Round 2
// 201.904 us; speedup vs baseline: 1.3145x; 1.3145x over previous
//
#include <hip/hip_runtime.h>
#include <hip/hip_bf16.h>

#define K_FEATS 256
#define C_FEATS 64
#define ROWS_PER_BLOCK 16

// ---------------------------------------------------------------------------
// ws layout (bytes):
//   hwn    (bf16)  : 0          .. 6,400,000      (50000*64*2)
//   eidx   (int)   : 6,400,000  .. 9,600,000      (800000*4)
//   deg    (int)   : 9,600,000  .. 9,800,000      (50000*4)
//   cursor (int)   : 9,800,000  ..10,000,000      (50000*4)   [adjacent to deg]
//   off    (int)   :10,000,000  ..10,200,000      (50000*4)
//   bsum   (int)   :10,200,000  ..10,201,024      (256*4)
// total ~10.2 MB (round-1 version already used 12.8 MB of ws successfully)
// ---------------------------------------------------------------------------

__global__ __launch_bounds__(256) void zero_ints(int* __restrict__ p, int n) {
    int i = blockIdx.x * 256 + threadIdx.x;
    if (i < n) p[i] = 0;
}

// ---------------------------------------------------------------------------
// Projection: hwn[n][c] = bf16( norm[n] * sum_k h[n][k] * w[k][c] )
// Same verified structure as round 1; now folds norm and stores bf16 to ws.
// ---------------------------------------------------------------------------
__global__ __launch_bounds__(256) void gemm_norm_kernel(
    const float* __restrict__ h, const float* __restrict__ w,
    const float* __restrict__ norm, __hip_bfloat16* __restrict__ hwn, int n_nodes)
{
    __shared__ float w_lds[K_FEATS * C_FEATS];          // 64 KB
    __shared__ float h_lds[ROWS_PER_BLOCK * K_FEATS];   // 16 KB

    const int tid = threadIdx.x;
    for (int i = tid; i < K_FEATS * C_FEATS / 4; i += 256) {
        reinterpret_cast<float4*>(w_lds)[i] = reinterpret_cast<const float4*>(w)[i];
    }
    const int row0 = blockIdx.x * ROWS_PER_BLOCK;
    const float4* hsrc = reinterpret_cast<const float4*>(h + (size_t)row0 * K_FEATS);
    const int rows_here = min(ROWS_PER_BLOCK, n_nodes - row0);
    for (int i = tid; i < rows_here * K_FEATS / 4; i += 256) {
        reinterpret_cast<float4*>(h_lds)[i] = hsrc[i];
    }
    __syncthreads();

    const int c  = tid & 63;
    const int rg = tid >> 6;
    float acc0 = 0.f, acc1 = 0.f, acc2 = 0.f, acc3 = 0.f;
    const float* h0 = &h_lds[(rg * 4 + 0) * K_FEATS];
    const float* h1 = &h_lds[(rg * 4 + 1) * K_FEATS];
    const float* h2 = &h_lds[(rg * 4 + 2) * K_FEATS];
    const float* h3 = &h_lds[(rg * 4 + 3) * K_FEATS];
    #pragma unroll 8
    for (int k = 0; k < K_FEATS; ++k) {
        const float wv = w_lds[k * C_FEATS + c];
        acc0 = fmaf(h0[k], wv, acc0);
        acc1 = fmaf(h1[k], wv, acc1);
        acc2 = fmaf(h2[k], wv, acc2);
        acc3 = fmaf(h3[k], wv, acc3);
    }
    const int r = row0 + rg * 4;
    if (r + 0 < n_nodes) hwn[(size_t)(r + 0) * C_FEATS + c] = __float2bfloat16(acc0 * norm[r + 0]);
    if (r + 1 < n_nodes) hwn[(size_t)(r + 1) * C_FEATS + c] = __float2bfloat16(acc1 * norm[r + 1]);
    if (r + 2 < n_nodes) hwn[(size_t)(r + 2) * C_FEATS + c] = __float2bfloat16(acc2 * norm[r + 2]);
    if (r + 3 < n_nodes) hwn[(size_t)(r + 3) * C_FEATS + c] = __float2bfloat16(acc3 * norm[r + 3]);
}

// ---------------------------------------------------------------------------
// CSR build: histogram -> 3-phase exclusive scan -> cursor scatter
// ---------------------------------------------------------------------------
__global__ __launch_bounds__(256) void hist_kernel(
    const int* __restrict__ dst, int* __restrict__ deg, int n_edges)
{
    int i = blockIdx.x * 256 + threadIdx.x;
    if (i < n_edges) atomicAdd(&deg[dst[i]], 1);
}

__global__ __launch_bounds__(256) void scan_block_kernel(
    const int* __restrict__ deg, int* __restrict__ off, int* __restrict__ bsum, int n)
{
    __shared__ int s[256];
    const int tid = threadIdx.x;
    const int i = blockIdx.x * 256 + tid;
    const int v = (i < n) ? deg[i] : 0;
    s[tid] = v;
    __syncthreads();
    #pragma unroll
    for (int d = 1; d < 256; d <<= 1) {
        int t = (tid >= d) ? s[tid - d] : 0;
        __syncthreads();
        s[tid] += t;
        __syncthreads();
    }
    if (i < n) off[i] = s[tid] - v;          // exclusive within block
    if (tid == 255) bsum[blockIdx.x] = s[255];
}

__global__ __launch_bounds__(256) void scan_partials_kernel(int* __restrict__ bsum, int nb)
{
    __shared__ int s[256];
    const int tid = threadIdx.x;
    const int v = (tid < nb) ? bsum[tid] : 0;
    s[tid] = v;
    __syncthreads();
    #pragma unroll
    for (int d = 1; d < 256; d <<= 1) {
        int t = (tid >= d) ? s[tid - d] : 0;
        __syncthreads();
        s[tid] += t;
        __syncthreads();
    }
    if (tid < nb) bsum[tid] = s[tid] - v;    // exclusive block offsets
}

__global__ __launch_bounds__(256) void scan_add_kernel(
    int* __restrict__ off, const int* __restrict__ bsum, int n)
{
    int i = blockIdx.x * 256 + threadIdx.x;
    if (i < n) off[i] += bsum[i >> 8];
}

__global__ __launch_bounds__(256) void scatter_kernel(
    const int* __restrict__ src, const int* __restrict__ dst,
    const int* __restrict__ off, int* __restrict__ cursor,
    int* __restrict__ eidx, int n_edges)
{
    int i = blockIdx.x * 256 + threadIdx.x;
    if (i < n_edges) {
        const int d = dst[i];
        const int p = atomicAdd(&cursor[d], 1);
        eidx[off[d] + p] = src[i];
    }
}

// ---------------------------------------------------------------------------
// Aggregate + finalize: one wave per dst node, lane = feature.
// out[n][c] = relu( norm[n] * sum_{e in CSR(n)} hwn[eidx[e]][c] + bias[c] )
// ---------------------------------------------------------------------------
__global__ __launch_bounds__(256) void aggregate_kernel(
    const __hip_bfloat16* __restrict__ hwn, const int* __restrict__ eidx,
    const int* __restrict__ off, const int* __restrict__ deg,
    const float* __restrict__ norm, const float* __restrict__ bias,
    float* __restrict__ out, int n_nodes)
{
    const int node = blockIdx.x * 4 + (threadIdx.x >> 6);
    if (node >= n_nodes) return;
    const int lane = threadIdx.x & 63;

    int e = off[node];
    const int end = e + deg[node];
    float acc = 0.f;
    for (; e + 4 <= end; e += 4) {
        const int i0 = eidx[e + 0];
        const int i1 = eidx[e + 1];
        const int i2 = eidx[e + 2];
        const int i3 = eidx[e + 3];
        const float v0 = __bfloat162float(hwn[(size_t)i0 * C_FEATS + lane]);
        const float v1 = __bfloat162float(hwn[(size_t)i1 * C_FEATS + lane]);
        const float v2 = __bfloat162float(hwn[(size_t)i2 * C_FEATS + lane]);
        const float v3 = __bfloat162float(hwn[(size_t)i3 * C_FEATS + lane]);
        acc += v0 + v1 + v2 + v3;
    }
    for (; e < end; ++e) {
        acc += __bfloat162float(hwn[(size_t)eidx[e] * C_FEATS + lane]);
    }
    const float o = fmaxf(fmaf(acc, norm[node], bias[lane]), 0.f);
    out[(size_t)node * C_FEATS + lane] = o;
}

extern "C" void kernel_launch(void* const* d_in, const int* in_sizes, int n_in,
                              void* d_out, int out_size, void* d_ws, size_t ws_size,
                              hipStream_t stream) {
    const float* h      = (const float*)d_in[0];
    const float* norm   = (const float*)d_in[1];
    const int*   src    = (const int*)d_in[2];
    const int*   dst    = (const int*)d_in[3];
    const float* weight = (const float*)d_in[4];
    const float* bias   = (const float*)d_in[5];

    const int n_nodes = in_sizes[1];
    const int n_edges = in_sizes[2];

    char* ws = (char*)d_ws;
    __hip_bfloat16* hwn = (__hip_bfloat16*)(ws + 0);
    int* eidx   = (int*)(ws + 6400000);
    int* deg    = (int*)(ws + 9600000);
    int* cursor = (int*)(ws + 9800000);   // adjacent to deg: zeroed together
    int* off    = (int*)(ws + 10000000);
    int* bsum   = (int*)(ws + 10200000);

    const int nb_scan = (n_nodes + 255) / 256;   // 196 for 50000 (fits 1 block)

    // 0) zero deg + cursor (adjacent, 2*n_nodes ints)
    zero_ints<<<(2 * n_nodes + 255) / 256, 256, 0, stream>>>(deg, 2 * n_nodes);
    // 1) projection with norm folded, bf16 output into ws
    gemm_norm_kernel<<<(n_nodes + ROWS_PER_BLOCK - 1) / ROWS_PER_BLOCK, 256, 0, stream>>>(
        h, weight, norm, hwn, n_nodes);
    // 2) CSR build
    hist_kernel<<<(n_edges + 255) / 256, 256, 0, stream>>>(dst, deg, n_edges);
    scan_block_kernel<<<nb_scan, 256, 0, stream>>>(deg, off, bsum, n_nodes);
    scan_partials_kernel<<<1, 256, 0, stream>>>(bsum, nb_scan);
    scan_add_kernel<<<nb_scan, 256, 0, stream>>>(off, bsum, n_nodes);
    scatter_kernel<<<(n_edges + 255) / 256, 256, 0, stream>>>(src, dst, off, cursor, eidx, n_edges);
    // 3) gather-aggregate + finalize (no f32 atomics anywhere)
    aggregate_kernel<<<(n_nodes + 3) / 4, 256, 0, stream>>>(
        hwn, eidx, off, deg, norm, bias, (float*)d_out, n_nodes);
}